// Round 3
// baseline (457.758 us; speedup 1.0000x reference)
//
#include <hip/hip_runtime.h>
#include <hip/hip_bf16.h>
#include <math.h>

// Problem constants
constexpr int Ncfg = 4096;
constexpr int Dcfg = 4096;
constexpr int Ocfg = 4096;
constexpr int Ecfg = 8;
constexpr int Rcfg = 16;
constexpr int KD   = Dcfg + Ecfg * Rcfg;   // 4224 fused-K
constexpr float ALPHA_C = 1.0f;
constexpr double TEMP_C = 1.0;

// Workspace layout (bytes)
constexpr size_t BT_OFF = 0;                                   // B'^T bf16 [O][KD]
constexpr size_t AP_OFF = BT_OFF + (size_t)Ocfg * KD * 2;      // A'   bf16 [N][KD]
constexpr size_t AT_OFF = AP_OFF + (size_t)Ncfg * KD * 2;      // lora_A^T bf16 [E][R][D]
constexpr size_t G_OFF  = AT_OFF + (size_t)Ecfg * Rcfg * Dcfg * 2; // gates f32 [N][16]

typedef short bf16x8 __attribute__((ext_vector_type(8)));
typedef float f32x4  __attribute__((ext_vector_type(4)));

__device__ __forceinline__ void async_load16(const __hip_bfloat16* g, __hip_bfloat16* l) {
  __builtin_amdgcn_global_load_lds((__attribute__((address_space(1))) void*)(g),
                                   (__attribute__((address_space(3))) void*)(l), 16, 0, 0);
}

// ---------------------------------------------------------------------------
// K0: lora_A (E,D,R) fp32 -> AT (E,R,D) bf16.  Tiny (3 us); separate launch
// because the mega-kernel's lora phase consumes AT.
// ---------------------------------------------------------------------------
__global__ void loraA_transpose_kernel(const float* __restrict__ A,
                                       __hip_bfloat16* __restrict__ AT) {
  const int e  = blockIdx.y;
  const int d0 = blockIdx.x * 256;
  const int tid = threadIdx.x;
  __shared__ float tile[256][17];
#pragma unroll
  for (int it = 0; it < 16; it++) {
    int idx = it * 256 + tid;
    int d = idx >> 4, rr = idx & 15;
    tile[d][rr] = A[((size_t)e * Dcfg + d0 + d) * Rcfg + rr];
  }
  __syncthreads();
#pragma unroll
  for (int rr = 0; rr < Rcfg; rr++) {
    AT[((size_t)e * Rcfg + rr) * Dcfg + d0 + tid] = __float2bfloat16(tile[tid][rr]);
  }
}

// ---------------------------------------------------------------------------
// Mega prep kernel.  Grid = 4480 blocks of 256 threads:
//   bid in [0,256)      : fused gates+scale+lora for rows [bid*16, bid*16+16)
//   bid in [256,4352)   : W (D,O) -> BT[o][0:4096] transpose+cast (64x64 tile)
//   bid in [4352,4480)  : lora_B (E,R,O) -> BT[o][4096:4224] transpose+cast
// All three families are mutually independent -> they overlap on the device
// instead of serializing across launches.
// ---------------------------------------------------------------------------
__global__ __launch_bounds__(256) void prep_main_kernel(
    const float* __restrict__ x,  const float* __restrict__ gw,
    const float* __restrict__ W,  const float* __restrict__ lB,
    const __hip_bfloat16* __restrict__ AT,
    float* __restrict__ gates, __hip_bfloat16* __restrict__ Ap,
    __hip_bfloat16* __restrict__ BT) {
  __shared__ union {
    struct {
      double lg[16][9];     // per-row logits
      float  gsh[16][9];    // per-row gates
      f32x4  red[4][8][64]; // cross-wave lora reduction
    } gl;
    float tile[64][65];     // transpose staging
  } sm;

  const int bid = blockIdx.x;
  const int tid = threadIdx.x;

  if (bid >= 256) {
    // ---------------- transpose families ----------------
    const float* src; int r0, c0, dstOff;
    if (bid < 4352) {           // W: 64x64 grid
      int id = bid - 256;
      src = W; r0 = (id & 63) * 64; c0 = (id >> 6) * 64; dstOff = 0;
    } else {                    // lB flat (128 x O): 2x64 grid
      int id = bid - 4352;
      src = lB; r0 = (id & 1) * 64; c0 = (id >> 1) * 64; dstOff = Dcfg;
    }
#pragma unroll
    for (int it = 0; it < 4; it++) {
      int flat = it * 256 + tid;
      int i = flat >> 4, f = flat & 15;
      float4 v = *(const float4*)(src + (size_t)(r0 + i) * Ocfg + c0 + 4 * f);
      sm.tile[i][4 * f + 0] = v.x;
      sm.tile[i][4 * f + 1] = v.y;
      sm.tile[i][4 * f + 2] = v.z;
      sm.tile[i][4 * f + 3] = v.w;
    }
    __syncthreads();
#pragma unroll
    for (int it = 0; it < 4; it++) {
      int flat = it * 256 + tid;
      int j = flat >> 4, q = flat & 15;
      union { ushort4 u; __hip_bfloat16 h[4]; } p;
      p.h[0] = __float2bfloat16(sm.tile[4 * q + 0][j]);
      p.h[1] = __float2bfloat16(sm.tile[4 * q + 1][j]);
      p.h[2] = __float2bfloat16(sm.tile[4 * q + 2][j]);
      p.h[3] = __float2bfloat16(sm.tile[4 * q + 3][j]);
      *(ushort4*)(BT + (size_t)(c0 + j) * KD + dstOff + r0 + 4 * q) = p.u;
    }
    return;
  }

  // ---------------- fused gates + base-scale + lora for 16 rows ----------------
  const int n0 = bid * 16;
  const int row = tid >> 4, sub = tid & 15;   // 16 threads per row
  const int n = n0 + row;
  const float4* xr4 = (const float4*)(x + (size_t)n * Dcfg);
  const float4* gw4 = (const float4*)gw;

  // Phase 1: fp64 gate logits (top-2 is a discrete decision; keep it exact).
  double acc[9];
#pragma unroll
  for (int e = 0; e < 9; e++) acc[e] = 0.0;
  for (int i = 0; i < 64; i++) {
    int fi = sub + 16 * i;                    // 16 lanes -> 256B coalesced
    float4 xv = xr4[fi];
#pragma unroll
    for (int e = 0; e < 9; e++) {
      float4 w = gw4[e * 1024 + fi];
      acc[e] += (double)xv.x * (double)w.x + (double)xv.y * (double)w.y +
                (double)xv.z * (double)w.z + (double)xv.w * (double)w.w;
    }
  }
#pragma unroll
  for (int off = 8; off >= 1; off >>= 1) {    // reduce within 16-lane row group
#pragma unroll
    for (int e = 0; e < 9; e++) acc[e] += __shfl_xor(acc[e], off, 64);
  }
  if (sub == 0) {
#pragma unroll
    for (int e = 0; e < 9; e++) sm.gl.lg[row][e] = acc[e];
  }
  __syncthreads();
  if (tid < 16) {
    double lg[9];
#pragma unroll
    for (int e = 0; e < 9; e++) lg[e] = sm.gl.lg[tid][e];
    // top-2 over experts 1..8, lowest index wins ties (jax top_k semantics)
    int i1 = 1;
    for (int e = 2; e <= 8; e++) if (lg[e] > lg[i1]) i1 = e;
    int i2 = -1; double v2 = -1e300;
    for (int e = 1; e <= 8; e++) if (e != i1 && lg[e] > v2) { v2 = lg[e]; i2 = e; }
    double vals[9];
    vals[0] = lg[0];
    for (int e = 1; e <= 8; e++) vals[e] = (e == i1 || e == i2) ? lg[e] : 0.0; // zeros, NOT -inf
    double mx = vals[0];
    for (int e = 1; e < 9; e++) mx = fmax(mx, vals[e]);
    double se = 0.0, ex[9];
    for (int e = 0; e < 9; e++) { ex[e] = exp((vals[e] - mx) / TEMP_C); se += ex[e]; }
    const int nn = n0 + tid;
    for (int e = 0; e < 9; e++) {
      float g = (float)(ex[e] / se);
      gates[nn * 16 + e] = g;
      sm.gl.gsh[tid][e] = g;
    }
  }
  __syncthreads();

  // Phase 2: base-scale writes A'[n,0:D] = bf16(g0 * x[n,:])  (x is L1/L2-hot)
  {
    const float g0 = sm.gl.gsh[row][0];
    __hip_bfloat16* ar = Ap + (size_t)n * KD;
    for (int i = 0; i < 64; i++) {
      int fi = sub + 16 * i;
      float4 xv = xr4[fi];
      union { ushort4 u; __hip_bfloat16 h[4]; } p;
      p.h[0] = __float2bfloat16(g0 * xv.x);
      p.h[1] = __float2bfloat16(g0 * xv.y);
      p.h[2] = __float2bfloat16(g0 * xv.z);
      p.h[3] = __float2bfloat16(g0 * xv.w);
      *(ushort4*)(ar + (size_t)fi * 4) = p.u;
    }
  }

  // Phase 3: lora t = x @ lora_A[e] via 16x16x32 bf16 MFMA, K split across
  // 4 waves (1024 each), LDS reduce, gated write to A'[n, 4096+e*16+r].
  // C/D layout: col(r) = lane&15, row = quad*4 + reg   [m89-verified]
  {
    const int wave = tid >> 6, lane = tid & 63;
    const int m = lane & 15, quad = lane >> 4;
    const int kbase = wave * 1024;
    f32x4 lacc[8] = {};
    const float* xrow = x + (size_t)(n0 + m) * Dcfg + kbase + quad * 8;
    const __hip_bfloat16* atb = AT + (size_t)m * Dcfg + kbase + quad * 8;
#pragma unroll 2
    for (int kb = 0; kb < 1024; kb += 32) {
      float4 x0 = *(const float4*)(xrow + kb);
      float4 x1 = *(const float4*)(xrow + kb + 4);
      union { bf16x8 v; __hip_bfloat16 h[8]; } a;
      a.h[0] = __float2bfloat16(x0.x); a.h[1] = __float2bfloat16(x0.y);
      a.h[2] = __float2bfloat16(x0.z); a.h[3] = __float2bfloat16(x0.w);
      a.h[4] = __float2bfloat16(x1.x); a.h[5] = __float2bfloat16(x1.y);
      a.h[6] = __float2bfloat16(x1.z); a.h[7] = __float2bfloat16(x1.w);
#pragma unroll
      for (int e = 0; e < Ecfg; e++) {
        bf16x8 b = *(const bf16x8*)(atb + (size_t)e * Rcfg * Dcfg + kb);
        lacc[e] = __builtin_amdgcn_mfma_f32_16x16x32_bf16(a.v, b, lacc[e], 0, 0, 0);
      }
    }
#pragma unroll
    for (int e = 0; e < Ecfg; e++) sm.gl.red[wave][e][lane] = lacc[e];
    __syncthreads();
#pragma unroll
    for (int ei = 0; ei < 2; ei++) {          // wave w -> experts 2w, 2w+1
      const int e = wave * 2 + ei;
      f32x4 s = sm.gl.red[0][e][lane] + sm.gl.red[1][e][lane] +
                sm.gl.red[2][e][lane] + sm.gl.red[3][e][lane];
#pragma unroll
      for (int rg = 0; rg < 4; rg++) {
        int nn = n0 + quad * 4 + rg;
        float g = sm.gl.gsh[quad * 4 + rg][1 + e];
        Ap[(size_t)nn * KD + Dcfg + e * Rcfg + m] =
            __float2bfloat16(ALPHA_C * g * s[rg]);
      }
    }
  }
}

// ---------------------------------------------------------------------------
// GEMM  out = A'(N x KD) @ B'(KD x O) + g0[n]*bias[o]   (m97 structure,
// frozen this round to isolate the prep changes)
// ---------------------------------------------------------------------------
__global__ __launch_bounds__(256) void gemm_kernel(
    const __hip_bfloat16* __restrict__ Ap, const __hip_bfloat16* __restrict__ BT,
    const float* __restrict__ gates, const float* __restrict__ bias,
    float* __restrict__ out) {
  __shared__ __hip_bfloat16 As[128 * 32];
  __shared__ __hip_bfloat16 Bs[128 * 32];
  const int tid = threadIdx.x;
  const int m0 = blockIdx.y * 128, n0 = blockIdx.x * 128;
  const int wave = tid >> 6, lane = tid & 63;
  const int wm = (wave & 1) * 64, wn = (wave >> 1) * 64;
  const int mr = lane & 15, quad = lane >> 4;

  f32x4 acc[4][4] = {};

  const int srow = tid >> 2;
  const int kc = (tid & 3) * 8;
  const __hip_bfloat16* gA0 = Ap + (size_t)(m0 + srow) * KD + kc;
  const __hip_bfloat16* gA1 = gA0 + (size_t)64 * KD;
  const __hip_bfloat16* gB0 = BT + (size_t)(n0 + srow) * KD + kc;
  const __hip_bfloat16* gB1 = gB0 + (size_t)64 * KD;
  __hip_bfloat16* lA0 = As + tid * 8;
  __hip_bfloat16* lA1 = As + 64 * 32 + tid * 8;
  __hip_bfloat16* lB0 = Bs + tid * 8;
  __hip_bfloat16* lB1 = Bs + 64 * 32 + tid * 8;

  for (int kb = 0; kb < KD; kb += 32) {
    __syncthreads();
    async_load16(gA0 + kb, lA0);
    async_load16(gA1 + kb, lA1);
    async_load16(gB0 + kb, lB0);
    async_load16(gB1 + kb, lB1);
    asm volatile("s_waitcnt vmcnt(0)" ::: "memory");
    __syncthreads();

    bf16x8 a[4], b[4];
#pragma unroll
    for (int i = 0; i < 4; i++)
      a[i] = *(const bf16x8*)&As[(wm + i * 16 + mr) * 32 + quad * 8];
#pragma unroll
    for (int j = 0; j < 4; j++)
      b[j] = *(const bf16x8*)&Bs[(wn + j * 16 + mr) * 32 + quad * 8];
#pragma unroll
    for (int i = 0; i < 4; i++)
#pragma unroll
      for (int j = 0; j < 4; j++)
        acc[i][j] = __builtin_amdgcn_mfma_f32_16x16x32_bf16(a[i], b[j], acc[i][j], 0, 0, 0);
  }

#pragma unroll
  for (int i = 0; i < 4; i++) {
    const int rowb = m0 + wm + i * 16 + quad * 4;
#pragma unroll
    for (int rg = 0; rg < 4; rg++) {
      const int row = rowb + rg;
      const float g0 = gates[row * 16];
#pragma unroll
      for (int j = 0; j < 4; j++) {
        const int col = n0 + wn + j * 16 + mr;
        out[(size_t)row * Ocfg + col] = acc[i][j][rg] + g0 * bias[col];
      }
    }
  }
}

// ---------------------------------------------------------------------------
extern "C" void kernel_launch(void* const* d_in, const int* in_sizes, int n_in,
                              void* d_out, int out_size, void* d_ws, size_t ws_size,
                              hipStream_t stream) {
  const float* x  = (const float*)d_in[0];
  const float* W  = (const float*)d_in[1];   // (D, O)
  const float* b  = (const float*)d_in[2];   // (O,)
  const float* lA = (const float*)d_in[3];   // (E, D, R)
  const float* lB = (const float*)d_in[4];   // (E, R, O)
  const float* gw = (const float*)d_in[5];   // (E+1, D)
  // d_in[6] = bvv, unused by the reference
  float* out = (float*)d_out;

  char* ws = (char*)d_ws;
  __hip_bfloat16* BT    = (__hip_bfloat16*)(ws + BT_OFF);
  __hip_bfloat16* Ap    = (__hip_bfloat16*)(ws + AP_OFF);
  __hip_bfloat16* AT    = (__hip_bfloat16*)(ws + AT_OFF);
  float*          gates = (float*)(ws + G_OFF);

  loraA_transpose_kernel<<<dim3(16, 8), 256, 0, stream>>>(lA, AT);
  prep_main_kernel<<<dim3(4480), 256, 0, stream>>>(x, gw, W, lB, AT, gates, Ap, BT);
  gemm_kernel<<<dim3(Ocfg / 128, Ncfg / 128), 256, 0, stream>>>(Ap, BT, gates, b, out);
}

// Round 4
// 424.548 us; speedup vs baseline: 1.0782x; 1.0782x over previous
//
#include <hip/hip_runtime.h>
#include <hip/hip_bf16.h>
#include <math.h>

// Problem constants
constexpr int Ncfg = 4096;
constexpr int Dcfg = 4096;
constexpr int Ocfg = 4096;
constexpr int Ecfg = 8;
constexpr int Rcfg = 16;
constexpr int KD   = Dcfg + Ecfg * Rcfg;   // 4224 fused-K
constexpr float ALPHA_C = 1.0f;
constexpr double TEMP_C = 1.0;

// Workspace layout (bytes)
constexpr size_t BT_OFF = 0;                                   // B'^T bf16 [O][KD]
constexpr size_t AP_OFF = BT_OFF + (size_t)Ocfg * KD * 2;      // A'   bf16 [N][KD]
constexpr size_t AT_OFF = AP_OFF + (size_t)Ncfg * KD * 2;      // lora_A^T bf16 [E][R][D]
constexpr size_t G_OFF  = AT_OFF + (size_t)Ecfg * Rcfg * Dcfg * 2; // gates f32 [N][16]

typedef short bf16x8 __attribute__((ext_vector_type(8)));
typedef float f32x4  __attribute__((ext_vector_type(4)));

__device__ __forceinline__ void async_load16(const __hip_bfloat16* g, __hip_bfloat16* l) {
  __builtin_amdgcn_global_load_lds((__attribute__((address_space(1))) void*)(g),
                                   (__attribute__((address_space(3))) void*)(l), 16, 0, 0);
}

// ---------------------------------------------------------------------------
// Launch 1: five MUTUALLY INDEPENDENT families in one wide kernel.
//   [0,    512): gates       — 8 rows/block, 2 rows/wave (halves gw L2 re-read)
//   [512, 4608): W (D,O) -> BT[o][0:4096] transpose+cast, 64x64 tiles
//   [4608,6656): x -> bf16 A'[n][0:4096]  (UNSCALED — gate-independent)
//   [6656,6784): lora_B (E*R,O) -> BT[o][4096:4224]
//   [6784,6912): lora_A (E,D,R) -> AT (E,R,D) bf16
// No intra-block phase serialization anywhere; union LDS is 17.4 KB max.
// ---------------------------------------------------------------------------
__global__ __launch_bounds__(256) void prep_parallel_kernel(
    const float* __restrict__ x,  const float* __restrict__ gw,
    const float* __restrict__ W,  const float* __restrict__ lB,
    const float* __restrict__ lA,
    float* __restrict__ gates, __hip_bfloat16* __restrict__ Ap,
    __hip_bfloat16* __restrict__ BT, __hip_bfloat16* __restrict__ AT) {
  __shared__ union {
    float tile[64][65];     // 64x64 transpose staging (+1 pad)
    float atile[256][17];   // loraA staging
  } sm;
  const int bid = blockIdx.x;
  const int tid = threadIdx.x;

  if (bid < 512) {
    // ---------------- gates: fp64 logits, top-2 sparse softmax ----------------
    const int wave = tid >> 6, lane = tid & 63;
    const int na = bid * 8 + wave * 2, nb = na + 1;   // 2 rows per wave
    const float4* xa4 = (const float4*)(x + (size_t)na * Dcfg);
    const float4* xb4 = (const float4*)(x + (size_t)nb * Dcfg);
    const float4* gw4 = (const float4*)gw;
    double accA[9], accB[9];
#pragma unroll
    for (int e = 0; e < 9; e++) { accA[e] = 0.0; accB[e] = 0.0; }
    for (int i = 0; i < 16; i++) {
      int fi = lane + 64 * i;
      float4 xa = xa4[fi], xb = xb4[fi];
#pragma unroll
      for (int e = 0; e < 9; e++) {
        float4 w = gw4[e * 1024 + fi];   // shared load serves both rows
        accA[e] += (double)xa.x * (double)w.x + (double)xa.y * (double)w.y +
                   (double)xa.z * (double)w.z + (double)xa.w * (double)w.w;
        accB[e] += (double)xb.x * (double)w.x + (double)xb.y * (double)w.y +
                   (double)xb.z * (double)w.z + (double)xb.w * (double)w.w;
      }
    }
#pragma unroll
    for (int off = 32; off >= 1; off >>= 1) {
#pragma unroll
      for (int e = 0; e < 9; e++) {
        accA[e] += __shfl_xor(accA[e], off, 64);
        accB[e] += __shfl_xor(accB[e], off, 64);
      }
    }
    if (lane == 0) {
#pragma unroll
      for (int r = 0; r < 2; r++) {
        double lg[9];
#pragma unroll
        for (int e = 0; e < 9; e++) lg[e] = r ? accB[e] : accA[e];
        // top-2 over experts 1..8, lowest index wins ties (jax top_k)
        int i1 = 1;
        for (int e = 2; e <= 8; e++) if (lg[e] > lg[i1]) i1 = e;
        int i2 = -1; double v2 = -1e300;
        for (int e = 1; e <= 8; e++) if (e != i1 && lg[e] > v2) { v2 = lg[e]; i2 = e; }
        double vals[9];
        vals[0] = lg[0];
        for (int e = 1; e <= 8; e++) vals[e] = (e == i1 || e == i2) ? lg[e] : 0.0; // zeros, NOT -inf
        double mx = vals[0];
        for (int e = 1; e < 9; e++) mx = fmax(mx, vals[e]);
        double se = 0.0, ex[9];
        for (int e = 0; e < 9; e++) { ex[e] = exp((vals[e] - mx) / TEMP_C); se += ex[e]; }
        const int n = r ? nb : na;
        for (int e = 0; e < 9; e++) gates[n * 16 + e] = (float)(ex[e] / se);
      }
    }
  } else if (bid < 6656 && bid >= 4608) {
    // ---------------- x -> bf16 cast (2 rows/block), unscaled ----------------
    const int n0 = (bid - 4608) * 2;
    const float4* xr = (const float4*)(x + (size_t)n0 * Dcfg);
#pragma unroll
    for (int it = 0; it < 8; it++) {
      int fi = it * 256 + tid;                 // [0,2048) over 2 rows
      int row = fi >> 10, c4 = fi & 1023;
      float4 v = xr[(size_t)row * 1024 + c4];
      union { ushort4 u; __hip_bfloat16 h[4]; } p;
      p.h[0] = __float2bfloat16(v.x);
      p.h[1] = __float2bfloat16(v.y);
      p.h[2] = __float2bfloat16(v.z);
      p.h[3] = __float2bfloat16(v.w);
      *(ushort4*)(Ap + (size_t)(n0 + row) * KD + 4 * c4) = p.u;
    }
  } else if (bid < 6784) {
    // ---------------- W / lora_B transpose+cast, 64x64 tile ----------------
    const float* src; int r0, c0, dstOff;
    if (bid < 4608) {          // W: id in [0,4096)
      int id = bid - 512;
      src = W; r0 = (id & 63) * 64; c0 = (id >> 6) * 64; dstOff = 0;
    } else {                   // lB flat (128 x O): id in [0,128)
      int id = bid - 6656;
      src = lB; r0 = (id & 1) * 64; c0 = (id >> 1) * 64; dstOff = Dcfg;
    }
#pragma unroll
    for (int it = 0; it < 4; it++) {
      int flat = it * 256 + tid;
      int i = flat >> 4, f = flat & 15;
      float4 v = *(const float4*)(src + (size_t)(r0 + i) * Ocfg + c0 + 4 * f);
      sm.tile[i][4 * f + 0] = v.x;
      sm.tile[i][4 * f + 1] = v.y;
      sm.tile[i][4 * f + 2] = v.z;
      sm.tile[i][4 * f + 3] = v.w;
    }
    __syncthreads();
#pragma unroll
    for (int it = 0; it < 4; it++) {
      int flat = it * 256 + tid;
      int j = flat >> 4, q = flat & 15;
      union { ushort4 u; __hip_bfloat16 h[4]; } p;
      p.h[0] = __float2bfloat16(sm.tile[4 * q + 0][j]);
      p.h[1] = __float2bfloat16(sm.tile[4 * q + 1][j]);
      p.h[2] = __float2bfloat16(sm.tile[4 * q + 2][j]);
      p.h[3] = __float2bfloat16(sm.tile[4 * q + 3][j]);
      *(ushort4*)(BT + (size_t)(c0 + j) * KD + dstOff + r0 + 4 * q) = p.u;
    }
  } else {
    // ---------------- lora_A (E,D,R) -> AT (E,R,D) bf16 ----------------
    const int id = bid - 6784;
    const int e = id >> 4, d0 = (id & 15) * 256;
#pragma unroll
    for (int it = 0; it < 16; it++) {
      int idx = it * 256 + tid;
      int d = idx >> 4, rr = idx & 15;
      sm.atile[d][rr] = lA[((size_t)e * Dcfg + d0 + d) * Rcfg + rr];
    }
    __syncthreads();
#pragma unroll
    for (int rr = 0; rr < Rcfg; rr++) {
      AT[((size_t)e * Rcfg + rr) * Dcfg + d0 + tid] = __float2bfloat16(sm.atile[tid][rr]);
    }
  }
}

// ---------------------------------------------------------------------------
// Launch 2: t[n,e,:] = x[n,:] @ lora_A[e] via 16x16x32 bf16 MFMA.
// 512 threads = 8 waves, K split 8x512 -> 2 waves/SIMD latency hiding.
// LDS reduce, then gated write A'[n, 4096+e*16+r] = bf16(ALPHA*g_{1+e}*t).
// C/D layout: col(r) = lane&15, row = quad*4 + reg   [m89-verified]
// ---------------------------------------------------------------------------
__global__ __launch_bounds__(512) void lora_t_kernel(
    const float* __restrict__ x, const __hip_bfloat16* __restrict__ AT,
    const float* __restrict__ gates, __hip_bfloat16* __restrict__ Ap) {
  const int n0 = blockIdx.x * 16;
  const int tid = threadIdx.x;
  const int wave = tid >> 6, lane = tid & 63;
  const int m = lane & 15, quad = lane >> 4;
  const int kbase = wave * 512;

  f32x4 acc[8] = {};
  const float* xrow = x + (size_t)(n0 + m) * Dcfg + kbase + quad * 8;
  const __hip_bfloat16* atb = AT + (size_t)m * Dcfg + kbase + quad * 8;
#pragma unroll 2
  for (int kb = 0; kb < 512; kb += 32) {
    float4 x0 = *(const float4*)(xrow + kb);
    float4 x1 = *(const float4*)(xrow + kb + 4);
    union { bf16x8 v; __hip_bfloat16 h[8]; } a;
    a.h[0] = __float2bfloat16(x0.x); a.h[1] = __float2bfloat16(x0.y);
    a.h[2] = __float2bfloat16(x0.z); a.h[3] = __float2bfloat16(x0.w);
    a.h[4] = __float2bfloat16(x1.x); a.h[5] = __float2bfloat16(x1.y);
    a.h[6] = __float2bfloat16(x1.z); a.h[7] = __float2bfloat16(x1.w);
#pragma unroll
    for (int e = 0; e < Ecfg; e++) {
      bf16x8 b = *(const bf16x8*)(atb + (size_t)e * Rcfg * Dcfg + kb);
      acc[e] = __builtin_amdgcn_mfma_f32_16x16x32_bf16(a.v, b, acc[e], 0, 0, 0);
    }
  }
  __shared__ f32x4 red[8][8][64];
#pragma unroll
  for (int e = 0; e < Ecfg; e++) red[wave][e][lane] = acc[e];
  __syncthreads();
  {
    const int e = wave;   // wave w -> expert w
    f32x4 s = red[0][e][lane];
#pragma unroll
    for (int w = 1; w < 8; w++) s += red[w][e][lane];
#pragma unroll
    for (int rg = 0; rg < 4; rg++) {
      int nn = n0 + quad * 4 + rg;
      float g = gates[nn * 16 + 1 + e];
      Ap[(size_t)nn * KD + Dcfg + e * Rcfg + m] = __float2bfloat16(ALPHA_C * g * s[rg]);
    }
  }
}

// ---------------------------------------------------------------------------
// Launch 3: GEMM with split K-loop (m97 structure).
//   loop K in [0,4096): acc += bf16(x) @ W          (ungated base)
//   acc *= g0[row]                                   (gate applied in regs)
//   loop K in [4096,4224): acc += gated-lora @ lora_B
//   epilogue: out = acc + g0*bias
// ---------------------------------------------------------------------------
__global__ __launch_bounds__(256) void gemm_kernel(
    const __hip_bfloat16* __restrict__ Ap, const __hip_bfloat16* __restrict__ BT,
    const float* __restrict__ gates, const float* __restrict__ bias,
    float* __restrict__ out) {
  __shared__ __hip_bfloat16 As[128 * 32];
  __shared__ __hip_bfloat16 Bs[128 * 32];
  const int tid = threadIdx.x;
  const int m0 = blockIdx.y * 128, n0 = blockIdx.x * 128;
  const int wave = tid >> 6, lane = tid & 63;
  const int wm = (wave & 1) * 64, wn = (wave >> 1) * 64;
  const int mr = lane & 15, quad = lane >> 4;

  f32x4 acc[4][4] = {};

  const int srow = tid >> 2;
  const int kc = (tid & 3) * 8;
  const __hip_bfloat16* gA0 = Ap + (size_t)(m0 + srow) * KD + kc;
  const __hip_bfloat16* gA1 = gA0 + (size_t)64 * KD;
  const __hip_bfloat16* gB0 = BT + (size_t)(n0 + srow) * KD + kc;
  const __hip_bfloat16* gB1 = gB0 + (size_t)64 * KD;
  __hip_bfloat16* lA0 = As + tid * 8;
  __hip_bfloat16* lA1 = As + 64 * 32 + tid * 8;
  __hip_bfloat16* lB0 = Bs + tid * 8;
  __hip_bfloat16* lB1 = Bs + 64 * 32 + tid * 8;

  auto kstep = [&](int kb) {
    __syncthreads();
    async_load16(gA0 + kb, lA0);
    async_load16(gA1 + kb, lA1);
    async_load16(gB0 + kb, lB0);
    async_load16(gB1 + kb, lB1);
    asm volatile("s_waitcnt vmcnt(0)" ::: "memory");
    __syncthreads();
    bf16x8 a[4], b[4];
#pragma unroll
    for (int i = 0; i < 4; i++)
      a[i] = *(const bf16x8*)&As[(wm + i * 16 + mr) * 32 + quad * 8];
#pragma unroll
    for (int j = 0; j < 4; j++)
      b[j] = *(const bf16x8*)&Bs[(wn + j * 16 + mr) * 32 + quad * 8];
#pragma unroll
    for (int i = 0; i < 4; i++)
#pragma unroll
      for (int j = 0; j < 4; j++)
        acc[i][j] = __builtin_amdgcn_mfma_f32_16x16x32_bf16(a[i], b[j], acc[i][j], 0, 0, 0);
  };

  for (int kb = 0; kb < Dcfg; kb += 32) kstep(kb);

  // apply g0 per output row (loaded here, outside the peak-pressure loop)
  float g0v[4][4];
#pragma unroll
  for (int i = 0; i < 4; i++) {
    const int rowb = m0 + wm + i * 16 + quad * 4;
#pragma unroll
    for (int rg = 0; rg < 4; rg++) g0v[i][rg] = gates[(rowb + rg) * 16];
  }
#pragma unroll
  for (int i = 0; i < 4; i++)
#pragma unroll
    for (int rg = 0; rg < 4; rg++)
#pragma unroll
      for (int j = 0; j < 4; j++) acc[i][j][rg] *= g0v[i][rg];

  for (int kb = Dcfg; kb < KD; kb += 32) kstep(kb);

#pragma unroll
  for (int i = 0; i < 4; i++) {
    const int rowb = m0 + wm + i * 16 + quad * 4;
#pragma unroll
    for (int rg = 0; rg < 4; rg++) {
      const int row = rowb + rg;
#pragma unroll
      for (int j = 0; j < 4; j++) {
        const int col = n0 + wn + j * 16 + mr;
        out[(size_t)row * Ocfg + col] = acc[i][j][rg] + g0v[i][rg] * bias[col];
      }
    }
  }
}

// ---------------------------------------------------------------------------
extern "C" void kernel_launch(void* const* d_in, const int* in_sizes, int n_in,
                              void* d_out, int out_size, void* d_ws, size_t ws_size,
                              hipStream_t stream) {
  const float* x  = (const float*)d_in[0];
  const float* W  = (const float*)d_in[1];   // (D, O)
  const float* b  = (const float*)d_in[2];   // (O,)
  const float* lA = (const float*)d_in[3];   // (E, D, R)
  const float* lB = (const float*)d_in[4];   // (E, R, O)
  const float* gw = (const float*)d_in[5];   // (E+1, D)
  // d_in[6] = bvv, unused by the reference
  float* out = (float*)d_out;

  char* ws = (char*)d_ws;
  __hip_bfloat16* BT    = (__hip_bfloat16*)(ws + BT_OFF);
  __hip_bfloat16* Ap    = (__hip_bfloat16*)(ws + AP_OFF);
  __hip_bfloat16* AT    = (__hip_bfloat16*)(ws + AT_OFF);
  float*          gates = (float*)(ws + G_OFF);

  prep_parallel_kernel<<<dim3(6912), 256, 0, stream>>>(x, gw, W, lB, lA, gates, Ap, BT, AT);
  lora_t_kernel<<<dim3(Ncfg / 16), 512, 0, stream>>>(x, AT, gates, Ap);
  gemm_kernel<<<dim3(Ocfg / 128, Ncfg / 128), 256, 0, stream>>>(Ap, BT, gates, b, out);
}

// Round 5
// 399.755 us; speedup vs baseline: 1.1451x; 1.0620x over previous
//
#include <hip/hip_runtime.h>
#include <hip/hip_bf16.h>
#include <math.h>

// Problem constants
constexpr int Ncfg = 4096;
constexpr int Dcfg = 4096;
constexpr int Ocfg = 4096;
constexpr int Ecfg = 8;
constexpr int Rcfg = 16;
constexpr int KD   = Dcfg + Ecfg * Rcfg;   // 4224 fused-K
constexpr float ALPHA_C = 1.0f;
constexpr double TEMP_C = 1.0;

// Workspace layout (bytes)
constexpr size_t BT_OFF = 0;                                   // B'^T bf16 [O][KD]
constexpr size_t AP_OFF = BT_OFF + (size_t)Ocfg * KD * 2;      // A'   bf16 [N][KD]
constexpr size_t AT_OFF = AP_OFF + (size_t)Ncfg * KD * 2;      // lora_A^T bf16 [E][R][D]
constexpr size_t G_OFF  = AT_OFF + (size_t)Ecfg * Rcfg * Dcfg * 2; // gates f32 [N][16]

typedef short bf16x8 __attribute__((ext_vector_type(8)));
typedef float f32x4  __attribute__((ext_vector_type(4)));

__device__ __forceinline__ void async_load16(const __hip_bfloat16* g, __hip_bfloat16* l) {
  __builtin_amdgcn_global_load_lds((__attribute__((address_space(1))) void*)(g),
                                   (__attribute__((address_space(3))) void*)(l), 16, 0, 0);
}

// ---------------------------------------------------------------------------
// Launch 1: four MUTUALLY INDEPENDENT families in one wide kernel.
//   [0,    512): gates + base-scale — 8 rows/block, 2 rows/wave.
//                Phase A: fp64 logits (gw load shared by both rows),
//                shuffle-reduce, lane0 top-2 sparse softmax (zeros NOT -inf),
//                writes gates[]. Phase B (same wave, registers+L2-hot x):
//                Ap[n][0:4096] = bf16(g0 * x[n]).
//   [512, 4608): W (D,O) -> BT[o][0:4096] transpose+cast, 64x64 tiles
//   [4608,4736): lora_B (E*R,O) -> BT[o][4096:4224]
//   [4736,4864): lora_A (E,D,R) -> AT (E,R,D) bf16
// Gates family uses no LDS; union LDS is the 64x65 transpose tile (17 KB).
// ---------------------------------------------------------------------------
__global__ __launch_bounds__(256) void prep_parallel_kernel(
    const float* __restrict__ x,  const float* __restrict__ gw,
    const float* __restrict__ W,  const float* __restrict__ lB,
    const float* __restrict__ lA,
    float* __restrict__ gates, __hip_bfloat16* __restrict__ Ap,
    __hip_bfloat16* __restrict__ BT, __hip_bfloat16* __restrict__ AT) {
  __shared__ union {
    float tile[64][65];     // 64x64 transpose staging (+1 pad)
    float atile[256][17];   // loraA staging
  } sm;
  const int bid = blockIdx.x;
  const int tid = threadIdx.x;

  if (bid < 512) {
    // ---------------- gates + base-scale ----------------
    const int wave = tid >> 6, lane = tid & 63;
    const int na = bid * 8 + wave * 2, nb = na + 1;   // 2 rows per wave
    const float4* xa4 = (const float4*)(x + (size_t)na * Dcfg);
    const float4* xb4 = (const float4*)(x + (size_t)nb * Dcfg);
    const float4* gw4 = (const float4*)gw;
    double accA[9], accB[9];
#pragma unroll
    for (int e = 0; e < 9; e++) { accA[e] = 0.0; accB[e] = 0.0; }
    for (int i = 0; i < 16; i++) {
      int fi = lane + 64 * i;
      float4 xa = xa4[fi], xb = xb4[fi];
#pragma unroll
      for (int e = 0; e < 9; e++) {
        float4 w = gw4[e * 1024 + fi];   // shared load serves both rows
        accA[e] += (double)xa.x * (double)w.x + (double)xa.y * (double)w.y +
                   (double)xa.z * (double)w.z + (double)xa.w * (double)w.w;
        accB[e] += (double)xb.x * (double)w.x + (double)xb.y * (double)w.y +
                   (double)xb.z * (double)w.z + (double)xb.w * (double)w.w;
      }
    }
#pragma unroll
    for (int off = 32; off >= 1; off >>= 1) {
#pragma unroll
      for (int e = 0; e < 9; e++) {
        accA[e] += __shfl_xor(accA[e], off, 64);
        accB[e] += __shfl_xor(accB[e], off, 64);
      }
    }
    float g0A_l = 0.f, g0B_l = 0.f;
    if (lane == 0) {
#pragma unroll
      for (int r = 0; r < 2; r++) {
        double lg[9];
#pragma unroll
        for (int e = 0; e < 9; e++) lg[e] = r ? accB[e] : accA[e];
        // top-2 over experts 1..8, lowest index wins ties (jax top_k)
        int i1 = 1;
        for (int e = 2; e <= 8; e++) if (lg[e] > lg[i1]) i1 = e;
        int i2 = -1; double v2 = -1e300;
        for (int e = 1; e <= 8; e++) if (e != i1 && lg[e] > v2) { v2 = lg[e]; i2 = e; }
        double vals[9];
        vals[0] = lg[0];
        for (int e = 1; e <= 8; e++) vals[e] = (e == i1 || e == i2) ? lg[e] : 0.0; // zeros, NOT -inf
        double mx = vals[0];
        for (int e = 1; e < 9; e++) mx = fmax(mx, vals[e]);
        double se = 0.0, ex[9];
        for (int e = 0; e < 9; e++) { ex[e] = exp((vals[e] - mx) / TEMP_C); se += ex[e]; }
        const int n = r ? nb : na;
        for (int e = 0; e < 9; e++) gates[n * 16 + e] = (float)(ex[e] / se);
        if (r == 0) g0A_l = (float)(ex[0] / se); else g0B_l = (float)(ex[0] / se);
      }
    }
    const float g0A = __shfl(g0A_l, 0, 64);
    const float g0B = __shfl(g0B_l, 0, 64);
    // Phase B: base-scale writes (x rows are L2-hot from phase A)
    __hip_bfloat16* ara = Ap + (size_t)na * KD;
    __hip_bfloat16* arb = Ap + (size_t)nb * KD;
    for (int i = 0; i < 16; i++) {
      int fi = lane + 64 * i;
      float4 xa = xa4[fi], xb = xb4[fi];
      union { ushort4 u; __hip_bfloat16 h[4]; } p;
      p.h[0] = __float2bfloat16(g0A * xa.x);
      p.h[1] = __float2bfloat16(g0A * xa.y);
      p.h[2] = __float2bfloat16(g0A * xa.z);
      p.h[3] = __float2bfloat16(g0A * xa.w);
      *(ushort4*)(ara + (size_t)fi * 4) = p.u;
      p.h[0] = __float2bfloat16(g0B * xb.x);
      p.h[1] = __float2bfloat16(g0B * xb.y);
      p.h[2] = __float2bfloat16(g0B * xb.z);
      p.h[3] = __float2bfloat16(g0B * xb.w);
      *(ushort4*)(arb + (size_t)fi * 4) = p.u;
    }
  } else if (bid < 4736) {
    // ---------------- W / lora_B transpose+cast, 64x64 tile ----------------
    const float* src; int r0, c0, dstOff;
    if (bid < 4608) {          // W: id in [0,4096)
      int id = bid - 512;
      src = W; r0 = (id & 63) * 64; c0 = (id >> 6) * 64; dstOff = 0;
    } else {                   // lB flat (128 x O): id in [0,128)
      int id = bid - 4608;
      src = lB; r0 = (id & 1) * 64; c0 = (id >> 1) * 64; dstOff = Dcfg;
    }
#pragma unroll
    for (int it = 0; it < 4; it++) {
      int flat = it * 256 + tid;
      int i = flat >> 4, f = flat & 15;
      float4 v = *(const float4*)(src + (size_t)(r0 + i) * Ocfg + c0 + 4 * f);
      sm.tile[i][4 * f + 0] = v.x;
      sm.tile[i][4 * f + 1] = v.y;
      sm.tile[i][4 * f + 2] = v.z;
      sm.tile[i][4 * f + 3] = v.w;
    }
    __syncthreads();
#pragma unroll
    for (int it = 0; it < 4; it++) {
      int flat = it * 256 + tid;
      int j = flat >> 4, q = flat & 15;
      union { ushort4 u; __hip_bfloat16 h[4]; } p;
      p.h[0] = __float2bfloat16(sm.tile[4 * q + 0][j]);
      p.h[1] = __float2bfloat16(sm.tile[4 * q + 1][j]);
      p.h[2] = __float2bfloat16(sm.tile[4 * q + 2][j]);
      p.h[3] = __float2bfloat16(sm.tile[4 * q + 3][j]);
      *(ushort4*)(BT + (size_t)(c0 + j) * KD + dstOff + r0 + 4 * q) = p.u;
    }
  } else {
    // ---------------- lora_A (E,D,R) -> AT (E,R,D) bf16 ----------------
    const int id = bid - 4736;
    const int e = id >> 4, d0 = (id & 15) * 256;
#pragma unroll
    for (int it = 0; it < 16; it++) {
      int idx = it * 256 + tid;
      int d = idx >> 4, rr = idx & 15;
      sm.atile[d][rr] = lA[((size_t)e * Dcfg + d0 + d) * Rcfg + rr];
    }
    __syncthreads();
#pragma unroll
    for (int rr = 0; rr < Rcfg; rr++) {
      AT[((size_t)e * Rcfg + rr) * Dcfg + d0 + tid] = __float2bfloat16(sm.atile[tid][rr]);
    }
  }
}

// ---------------------------------------------------------------------------
// Launch 2: t[n,e,:] = x[n,:] @ lora_A[e] via 16x16x32 bf16 MFMA.
// 512 threads = 8 waves, K split 8x512 -> 2 waves/SIMD latency hiding.
// LDS reduce, then gated write A'[n, 4096+e*16+r] = bf16(ALPHA*g_{1+e}*t).
// C/D layout: col(r) = lane&15, row = quad*4 + reg   [m89-verified]
// ---------------------------------------------------------------------------
__global__ __launch_bounds__(512) void lora_t_kernel(
    const float* __restrict__ x, const __hip_bfloat16* __restrict__ AT,
    const float* __restrict__ gates, __hip_bfloat16* __restrict__ Ap) {
  const int n0 = blockIdx.x * 16;
  const int tid = threadIdx.x;
  const int wave = tid >> 6, lane = tid & 63;
  const int m = lane & 15, quad = lane >> 4;
  const int kbase = wave * 512;

  f32x4 acc[8] = {};
  const float* xrow = x + (size_t)(n0 + m) * Dcfg + kbase + quad * 8;
  const __hip_bfloat16* atb = AT + (size_t)m * Dcfg + kbase + quad * 8;
#pragma unroll 2
  for (int kb = 0; kb < 512; kb += 32) {
    float4 x0 = *(const float4*)(xrow + kb);
    float4 x1 = *(const float4*)(xrow + kb + 4);
    union { bf16x8 v; __hip_bfloat16 h[8]; } a;
    a.h[0] = __float2bfloat16(x0.x); a.h[1] = __float2bfloat16(x0.y);
    a.h[2] = __float2bfloat16(x0.z); a.h[3] = __float2bfloat16(x0.w);
    a.h[4] = __float2bfloat16(x1.x); a.h[5] = __float2bfloat16(x1.y);
    a.h[6] = __float2bfloat16(x1.z); a.h[7] = __float2bfloat16(x1.w);
#pragma unroll
    for (int e = 0; e < Ecfg; e++) {
      bf16x8 b = *(const bf16x8*)(atb + (size_t)e * Rcfg * Dcfg + kb);
      acc[e] = __builtin_amdgcn_mfma_f32_16x16x32_bf16(a.v, b, acc[e], 0, 0, 0);
    }
  }
  __shared__ f32x4 red[8][8][64];
#pragma unroll
  for (int e = 0; e < Ecfg; e++) red[wave][e][lane] = acc[e];
  __syncthreads();
  {
    const int e = wave;   // wave w -> expert w
    f32x4 s = red[0][e][lane];
#pragma unroll
    for (int w = 1; w < 8; w++) s += red[w][e][lane];
#pragma unroll
    for (int rg = 0; rg < 4; rg++) {
      int nn = n0 + quad * 4 + rg;
      float g = gates[nn * 16 + 1 + e];
      Ap[(size_t)nn * KD + Dcfg + e * Rcfg + m] = __float2bfloat16(ALPHA_C * g * s[rg]);
    }
  }
}

// ---------------------------------------------------------------------------
// Launch 3: GEMM  out = A'(N x KD) @ B'(KD x O) + g0[n]*bias[o]
// EXACT round-2 body (196.5 us, VALUBusy 11.8) — the round-4 split-K variant
// regressed codegen (VALUBusy 30.7, +27 us). Do not restructure this loop.
// ---------------------------------------------------------------------------
__global__ __launch_bounds__(256) void gemm_kernel(
    const __hip_bfloat16* __restrict__ Ap, const __hip_bfloat16* __restrict__ BT,
    const float* __restrict__ gates, const float* __restrict__ bias,
    float* __restrict__ out) {
  __shared__ __hip_bfloat16 As[128 * 32];
  __shared__ __hip_bfloat16 Bs[128 * 32];
  const int tid = threadIdx.x;
  const int m0 = blockIdx.y * 128, n0 = blockIdx.x * 128;
  const int wave = tid >> 6, lane = tid & 63;
  const int wm = (wave & 1) * 64, wn = (wave >> 1) * 64;
  const int mr = lane & 15, quad = lane >> 4;

  f32x4 acc[4][4] = {};

  const int srow = tid >> 2;
  const int kc = (tid & 3) * 8;
  const __hip_bfloat16* gA0 = Ap + (size_t)(m0 + srow) * KD + kc;
  const __hip_bfloat16* gA1 = gA0 + (size_t)64 * KD;
  const __hip_bfloat16* gB0 = BT + (size_t)(n0 + srow) * KD + kc;
  const __hip_bfloat16* gB1 = gB0 + (size_t)64 * KD;
  __hip_bfloat16* lA0 = As + tid * 8;
  __hip_bfloat16* lA1 = As + 64 * 32 + tid * 8;
  __hip_bfloat16* lB0 = Bs + tid * 8;
  __hip_bfloat16* lB1 = Bs + 64 * 32 + tid * 8;

  for (int kb = 0; kb < KD; kb += 32) {
    __syncthreads();
    async_load16(gA0 + kb, lA0);
    async_load16(gA1 + kb, lA1);
    async_load16(gB0 + kb, lB0);
    async_load16(gB1 + kb, lB1);
    asm volatile("s_waitcnt vmcnt(0)" ::: "memory");
    __syncthreads();

    bf16x8 a[4], b[4];
#pragma unroll
    for (int i = 0; i < 4; i++)
      a[i] = *(const bf16x8*)&As[(wm + i * 16 + mr) * 32 + quad * 8];
#pragma unroll
    for (int j = 0; j < 4; j++)
      b[j] = *(const bf16x8*)&Bs[(wn + j * 16 + mr) * 32 + quad * 8];
#pragma unroll
    for (int i = 0; i < 4; i++)
#pragma unroll
      for (int j = 0; j < 4; j++)
        acc[i][j] = __builtin_amdgcn_mfma_f32_16x16x32_bf16(a[i], b[j], acc[i][j], 0, 0, 0);
  }

#pragma unroll
  for (int i = 0; i < 4; i++) {
    const int rowb = m0 + wm + i * 16 + quad * 4;
#pragma unroll
    for (int rg = 0; rg < 4; rg++) {
      const int row = rowb + rg;
      const float g0 = gates[row * 16];
#pragma unroll
      for (int j = 0; j < 4; j++) {
        const int col = n0 + wn + j * 16 + mr;
        out[(size_t)row * Ocfg + col] = acc[i][j][rg] + g0 * bias[col];
      }
    }
  }
}

// ---------------------------------------------------------------------------
extern "C" void kernel_launch(void* const* d_in, const int* in_sizes, int n_in,
                              void* d_out, int out_size, void* d_ws, size_t ws_size,
                              hipStream_t stream) {
  const float* x  = (const float*)d_in[0];
  const float* W  = (const float*)d_in[1];   // (D, O)
  const float* b  = (const float*)d_in[2];   // (O,)
  const float* lA = (const float*)d_in[3];   // (E, D, R)
  const float* lB = (const float*)d_in[4];   // (E, R, O)
  const float* gw = (const float*)d_in[5];   // (E+1, D)
  // d_in[6] = bvv, unused by the reference
  float* out = (float*)d_out;

  char* ws = (char*)d_ws;
  __hip_bfloat16* BT    = (__hip_bfloat16*)(ws + BT_OFF);
  __hip_bfloat16* Ap    = (__hip_bfloat16*)(ws + AP_OFF);
  __hip_bfloat16* AT    = (__hip_bfloat16*)(ws + AT_OFF);
  float*          gates = (float*)(ws + G_OFF);

  prep_parallel_kernel<<<dim3(4864), 256, 0, stream>>>(x, gw, W, lB, lA, gates, Ap, BT, AT);
  lora_t_kernel<<<dim3(Ncfg / 16), 512, 0, stream>>>(x, AT, gates, Ap);
  gemm_kernel<<<dim3(Ocfg / 128, Ncfg / 128), 256, 0, stream>>>(Ap, BT, gates, b, out);
}